// Round 6
// baseline (423.723 us; speedup 1.0000x reference)
//
#include <hip/hip_runtime.h>
#include <hip/hip_bf16.h>

typedef __bf16 bf16;
typedef __bf16 bf16x8 __attribute__((ext_vector_type(8)));
typedef float f32x4 __attribute__((ext_vector_type(4)));
typedef unsigned short u16;
typedef unsigned int u32;

// round-to-nearest-even f32 -> bf16 bits (host-side prep kernels)
__device__ __forceinline__ u16 f2bf_bits(float f) {
    union { float f; u32 u; } v;
    v.f = f;
    u32 r = v.u + 0x7FFFu + ((v.u >> 16) & 1u);
    return (u16)(r >> 16);
}

// natural pack: compiler emits v_cvt_pk_bf16_f32 (RNE)
__device__ __forceinline__ u32 pack_bf2(float a, float b) {
    union { __bf16 h[2]; u32 u; } v;
    v.h[0] = (__bf16)a;
    v.h[1] = (__bf16)b;
    return v.u;
}

__device__ __forceinline__ void gload_lds16(const void* g, void* l) {
    __builtin_amdgcn_global_load_lds((const __attribute__((address_space(1))) void*)g,
                                     (__attribute__((address_space(3))) void*)l, 16, 0, 0);
}

// ---------------------------------------------------------------------------
// Prep kernels
// ---------------------------------------------------------------------------

__global__ __launch_bounds__(256) void cvt_bf16_kernel(const float* __restrict__ in,
                                                       u32* __restrict__ out, int n4) {
    int i = blockIdx.x * 256 + threadIdx.x;
    if (i < n4) {
        float4 v = reinterpret_cast<const float4*>(in)[i];
        u32 lo = (u32)f2bf_bits(v.x) | ((u32)f2bf_bits(v.y) << 16);
        u32 hi = (u32)f2bf_bits(v.z) | ((u32)f2bf_bits(v.w) << 16);
        reinterpret_cast<uint2*>(out)[i] = make_uint2(lo, hi);
    }
}

// out[n][k] = bf16( sum_r in[r*slab + k*N + n] ), K,N multiples of 32
__global__ __launch_bounds__(256) void transpose_sum_bf16(const float* __restrict__ in,
                                                          u16* __restrict__ out,
                                                          int K, int N, int R, long slab) {
    __shared__ float tile[32][33];
    int x = threadIdx.x & 31, ty = threadIdx.x >> 5;
    int k0 = blockIdx.y * 32, n0 = blockIdx.x * 32;
    for (int yy = ty; yy < 32; yy += 8) {
        float s = 0.f;
        for (int r = 0; r < R; ++r)
            s += in[(size_t)r * slab + (size_t)(k0 + yy) * N + n0 + x];
        tile[yy][x] = s;
    }
    __syncthreads();
    for (int yy = ty; yy < 32; yy += 8)
        out[(size_t)(n0 + yy) * K + k0 + x] = f2bf_bits(tile[x][yy]);
}

// bt[o] = sum_r text_w[r][1024][o] + text_b[r][o]
__global__ __launch_bounds__(256) void btfull_kernel(const float* __restrict__ tw,
                                                     const float* __restrict__ tb,
                                                     float* __restrict__ bt) {
    int o = blockIdx.x * 256 + threadIdx.x;
    float s = 0.f;
    for (int r = 0; r < 4; ++r)
        s += tw[(size_t)r * 1025 * 1024 + (size_t)1024 * 1024 + o] + tb[r * 1024 + o];
    bt[o] = s;
}

// wsum[i][o] = sum_r lat_w[r][i][o]  (i in [0,257))
__global__ __launch_bounds__(256) void latw_sum_kernel(const float* __restrict__ lw,
                                                       float* __restrict__ wsum) {
    int i = blockIdx.x * 256 + threadIdx.x;
    if (i < 257 * 1024) {
        float s = 0.f;
        for (int r = 0; r < 4; ++r) s += lw[(size_t)r * 257 * 1024 + i];
        wsum[i] = s;
    }
}

// lf[b][o] = sum_{i<256} latent[b][i]*wsum[i][o] + wsum[256][o] + sum_r lat_b[r][o]
__global__ __launch_bounds__(256) void latfuse_kernel(const float* __restrict__ latent,
                                                      const float* __restrict__ wsum,
                                                      const float* __restrict__ lb,
                                                      float* __restrict__ lf) {
    __shared__ float lat[256];
    const int b = blockIdx.y;
    const int o = blockIdx.x * 256 + threadIdx.x;
    lat[threadIdx.x] = latent[b * 256 + threadIdx.x];
    __syncthreads();
    float acc = wsum[(size_t)256 * 1024 + o];
    for (int r = 0; r < 4; ++r) acc += lb[r * 1024 + o];
#pragma unroll 8
    for (int i = 0; i < 256; ++i) acc += lat[i] * wsum[(size_t)i * 1024 + o];
    lf[b * 1024 + o] = acc;
}

// ---------------------------------------------------------------------------
// GEMM: C[M,N] = A[M,K] @ BT[N,K]^T
// EPI 1: +bias[col] -> f32
// EPI 2: +bias[row], * lf[(col>>11)][row] -> bf16   (transposed value-fusion)
// EPI 3: +bias[col], then * 0.125*log2e for col<1024 (pre-scaled q) -> bf16
// m97 structure: 128x128 tile, BK=64, 4 waves, global_load_lds, linear LDS.
// ---------------------------------------------------------------------------
template <int EPI>
__global__ __launch_bounds__(256) void gemm_bt(const bf16* __restrict__ A, int lda,
                                               const bf16* __restrict__ BT, int ldb,
                                               void* __restrict__ Cout, int ldc, int K,
                                               const float* __restrict__ bias,
                                               const float* __restrict__ scale) {
    __shared__ __align__(16) char As[16384];  // 128 rows x 64 bf16, linear
    __shared__ __align__(16) char Bs[16384];
    const int tid = threadIdx.x;
    const int w = tid >> 6, l = tid & 63;

    // XCD-aware bijective swizzle (grids here are multiples of 8)
    const int nwgx = gridDim.x;
    const int nwg = nwgx * gridDim.y;
    const int wgid = blockIdx.y * nwgx + blockIdx.x;
    const int swz = (wgid & 7) * (nwg >> 3) + (wgid >> 3);
    const int m0 = (swz / nwgx) * 128, n0 = (swz % nwgx) * 128;
    const int wr = (w >> 1) * 64, wc = (w & 1) * 64;

    f32x4 acc[4][4] = {};
    const int kIters = K >> 6;

    const int srow = tid >> 3;             // 0..31
    const int scol = (tid & 7) * 8;        // element col within BK=64
    const size_t aBase = (size_t)(m0 + srow) * lda + scol;
    const size_t bBase = (size_t)(n0 + srow) * ldb + scol;
    char* AsW = As + w * 1024;             // wave-uniform LDS base
    char* BsW = Bs + w * 1024;

    for (int kt = 0; kt < kIters; ++kt) {
        const int kk = kt << 6;
#pragma unroll
        for (int i = 0; i < 4; ++i) {
            gload_lds16(A + aBase + (size_t)(i * 32) * lda + kk, AsW + i * 4096);
            gload_lds16(BT + bBase + (size_t)(i * 32) * ldb + kk, BsW + i * 4096);
        }
        __syncthreads();  // drains vmcnt -> LDS tile ready
#pragma unroll
        for (int dc = 0; dc < 2; ++dc) {
            bf16x8 af[4], bfr[4];
#pragma unroll
            for (int m = 0; m < 4; ++m) {
                int off = (wr + m * 16 + (l & 15)) * 128 + dc * 64 + (l >> 4) * 16;
                af[m] = *reinterpret_cast<const bf16x8*>(As + off);
            }
#pragma unroll
            for (int n = 0; n < 4; ++n) {
                int off = (wc + n * 16 + (l & 15)) * 128 + dc * 64 + (l >> 4) * 16;
                bfr[n] = *reinterpret_cast<const bf16x8*>(Bs + off);
            }
#pragma unroll
            for (int m = 0; m < 4; ++m)
#pragma unroll
                for (int n = 0; n < 4; ++n)
                    acc[m][n] = __builtin_amdgcn_mfma_f32_16x16x32_bf16(af[m], bfr[n], acc[m][n], 0, 0, 0);
        }
        __syncthreads();  // tile consumed, safe to overwrite
    }

    const bool qtile = (EPI == 3) && (n0 < 1024);  // block-uniform
#pragma unroll
    for (int m = 0; m < 4; ++m) {
#pragma unroll
        for (int n = 0; n < 4; ++n) {
#pragma unroll
            for (int r = 0; r < 4; ++r) {
                int grow = m0 + wr + m * 16 + (l >> 4) * 4 + r;
                int gcol = n0 + wc + n * 16 + (l & 15);
                float v = acc[m][n][r];
                if (EPI == 1 || EPI == 3) v += bias[gcol];
                if (EPI == 3 && qtile) v *= 0.18033688011f;  // 0.125*log2(e)
                if (EPI == 2) {
                    v += bias[grow];
                    v *= scale[((gcol >> 11) << 10) | grow];
                }
                if (EPI == 1)
                    reinterpret_cast<float*>(Cout)[(size_t)grow * ldc + gcol] = v;
                else
                    reinterpret_cast<u16*>(Cout)[(size_t)grow * ldc + gcol] = f2bf_bits(v);
            }
        }
    }
}

// ---------------------------------------------------------------------------
// Flash attention, causal. qkv bf16 [8192][3072] (q pre-scaled | k | v cols),
// vfT bf16 [1024 o][8192 s], out bf16 [8192][1024].
// grid (16, 64) = 1024 blocks (4/CU): block handles q-tiles {x, 31-x} over
// 32 tiles of 64 rows (balanced causal pairing, 33 kv-tiles per block).
// 256 threads = 4 waves x 16 q-rows. K/V^T double-buffered in LDS (32 KB).
// P never touches LDS: cvt_pk + shfl_xor register re-layout into PV A-frags.
// NOTE: no min-waves pin -- (256,4) forced VGPR<=128 and spilled (R4).
// ---------------------------------------------------------------------------
__global__ __launch_bounds__(256) void attn_kernel(const bf16* __restrict__ qkv,
                                                   const bf16* __restrict__ vfT,
                                                   u16* __restrict__ out) {
    __shared__ __align__(16) char Kl[2][8192];     // [buf][64 kv][64 d] chunk-swizzled
    __shared__ __align__(16) char Vt[2][8192];     // [buf][64 hd][64 kv] chunk-swizzled
    const int tid = threadIdx.x, w = tid >> 6, l = tid & 63;
    const int bh = blockIdx.y, b = bh >> 4, h = bh & 15;

    // staging geometry: wave w covers LDS rows w*8+i*32+(l>>3), chunk l&7;
    // source chunk pre-swizzled: cs = (l&7) ^ (l>>3)
    const int srowL = (l >> 3);                    // 0..7 within 8-row stripe
    const int cs = ((l & 7) ^ srowL) * 8;          // element offset of source chunk

    for (int ph = 0; ph < 2; ++ph) {
        const int qt = ph ? (31 - blockIdx.x) : blockIdx.x;
        const int q0 = qt * 64;
        const size_t rowQ = (size_t)(b * 2048 + q0 + w * 16);

        // Q fragments (B-operand layout for swapped QK^T); q pre-scaled
        bf16x8 qfr[2];
#pragma unroll
        for (int dc = 0; dc < 2; ++dc)
            qfr[dc] = *reinterpret_cast<const bf16x8*>(
                qkv + (rowQ + (l & 15)) * 3072 + h * 64 + dc * 32 + (l >> 4) * 8);

        f32x4 oacc[4] = {};
        float mrun = -1e30f;
        float lrun = 0.f;
        const int nt = qt + 1;

        auto stage = [&](int t, int buf) {
            const size_t kvb = (size_t)(b * 2048 + t * 64);
#pragma unroll
            for (int i = 0; i < 2; ++i) {
                int r = w * 8 + i * 32 + srowL;
                gload_lds16(qkv + (kvb + r) * 3072 + 1024 + h * 64 + cs,
                            Kl[buf] + w * 1024 + i * 4096);
                gload_lds16(vfT + (size_t)(h * 64 + r) * 8192 + kvb + cs,
                            Vt[buf] + w * 1024 + i * 4096);
            }
        };

        __syncthreads();   // previous phase fully consumed before restaging
        stage(0, 0);
        int cur = 0;
        for (int t = 0; t < nt; ++t) {
            __syncthreads();  // vmcnt(0)+barrier: buf[cur] ready, buf[cur^1] free
            if (t + 1 < nt) stage(t + 1, cur ^ 1);
            const int kv0 = t * 64;
            const char* Kb = Kl[cur];
            const char* Vb = Vt[cur];
            // QK^T (swapped): sacc[kf] = S^T[kv, q], already in log2 units
            f32x4 sacc[4] = {};
            __builtin_amdgcn_s_setprio(1);
#pragma unroll
            for (int dc = 0; dc < 2; ++dc) {
#pragma unroll
                for (int kf = 0; kf < 4; ++kf) {
                    int row = kf * 16 + (l & 15);
                    int off = (row * 128 + dc * 64 + (l >> 4) * 16) ^ ((row & 7) << 4);
                    bf16x8 kfr = *reinterpret_cast<const bf16x8*>(Kb + off);
                    sacc[kf] = __builtin_amdgcn_mfma_f32_16x16x32_bf16(
                        kfr, qfr[dc], sacc[kf], 0, 0, 0);
                }
            }
            __builtin_amdgcn_s_setprio(0);
            const bool needMask = (kv0 + 63) > (q0 + w * 16);
            const int qg = q0 + w * 16 + (l & 15);
            float p[4][4];
            float tmax = -1e30f;
#pragma unroll
            for (int kf = 0; kf < 4; ++kf)
#pragma unroll
                for (int r = 0; r < 4; ++r) {
                    float s = sacc[kf][r];
                    if (needMask) {
                        int kvg = kv0 + kf * 16 + (l >> 4) * 4 + r;
                        if (kvg > qg) s = -1e30f;
                    }
                    p[kf][r] = s;
                    tmax = fmaxf(tmax, s);
                }
            tmax = fmaxf(tmax, __shfl_xor(tmax, 16));
            tmax = fmaxf(tmax, __shfl_xor(tmax, 32));
            // defer-max (T13): only rescale when max grows by > 8 (log2 domain)
            if (!__all(tmax <= mrun + 8.f)) {
                float mnew = fmaxf(mrun, tmax);
                float alpha = exp2f(mrun - mnew);
                mrun = mnew;
                lrun *= alpha;
#pragma unroll
                for (int r = 0; r < 4; ++r) {
                    float al = __shfl(alpha, (l >> 4) * 4 + r);
#pragma unroll
                    for (int hf = 0; hf < 4; ++hf) oacc[hf][r] *= al;
                }
            }
            const float m = mrun;
            float rsum = 0.f;
#pragma unroll
            for (int kf = 0; kf < 4; ++kf) {
                float p0 = exp2f(p[kf][0] - m), p1 = exp2f(p[kf][1] - m);
                float p2 = exp2f(p[kf][2] - m), p3 = exp2f(p[kf][3] - m);
                p[kf][0] = p0; p[kf][1] = p1; p[kf][2] = p2; p[kf][3] = p3;
                rsum += (p0 + p1) + (p2 + p3);
            }
            rsum += __shfl_xor(rsum, 16);
            rsum += __shfl_xor(rsum, 32);
            lrun += rsum;
            // pack to bf16 pairs: c[kf][h] = (P[kv=kf*16+g*4+2h], kv+1)
            u32 c[4][2];
#pragma unroll
            for (int kf = 0; kf < 4; ++kf) {
                c[kf][0] = pack_bf2(p[kf][0], p[kf][1]);
                c[kf][1] = pack_bf2(p[kf][2], p[kf][3]);
            }
            // register re-layout to PV A-frag: lane needs kv=kc*32+g*8+j.
            // routes (verified): g01: A<-A.even, B<-C.even, C<-A.odd, D<-C.odd
            //                    g23: A<-B.even, B<-D.even, C<-B.odd, D<-D.odd
            bf16x8 pa[2];
#pragma unroll
            for (int kc = 0; kc < 2; ++kc) {
                u32 wlo[2], whi[2];
#pragma unroll
                for (int hh = 0; hh < 2; ++hh) {
                    u32 oe = c[2 * kc][hh], oo = c[2 * kc + 1][hh];
                    u32 xoe = (u32)__shfl_xor((int)oe, 32);
                    u32 xoo = (u32)__shfl_xor((int)oo, 32);
                    u32 P1 = (l & 32) ? xoo : oe;
                    u32 P2 = (l & 32) ? oo : xoe;
                    u32 z = (l & 16) ? P1 : P2;
                    u32 xz = (u32)__shfl_xor((int)z, 16);
                    wlo[hh] = (l & 16) ? xz : P1;
                    whi[hh] = (l & 16) ? P2 : xz;
                }
                union { u32 u[4]; bf16x8 v; } pv;
                pv.u[0] = wlo[0]; pv.u[1] = wlo[1];
                pv.u[2] = whi[0]; pv.u[3] = whi[1];
                pa[kc] = pv.v;
            }
            // PV: oacc[hf] += P[q][kv] * V^T[hd][kv]^T
            __builtin_amdgcn_s_setprio(1);
#pragma unroll
            for (int kc = 0; kc < 2; ++kc) {
#pragma unroll
                for (int hf = 0; hf < 4; ++hf) {
                    int hd = hf * 16 + (l & 15);
                    int off = (hd * 128 + kc * 64 + (l >> 4) * 16) ^ ((hd & 7) << 4);
                    bf16x8 vb = *reinterpret_cast<const bf16x8*>(Vb + off);
                    oacc[hf] = __builtin_amdgcn_mfma_f32_16x16x32_bf16(
                        pa[kc], vb, oacc[hf], 0, 0, 0);
                }
            }
            __builtin_amdgcn_s_setprio(0);
            cur ^= 1;
        }

#pragma unroll
        for (int r = 0; r < 4; ++r) {
            float linv = 1.0f / __shfl(lrun, (l >> 4) * 4 + r);
            size_t grow = rowQ + (l >> 4) * 4 + r;
#pragma unroll
            for (int hf = 0; hf < 4; ++hf)
                out[grow * 1024 + h * 64 + hf * 16 + (l & 15)] =
                    f2bf_bits(oacc[hf][r] * linv);
        }
    }
}

// ---------------------------------------------------------------------------

extern "C" void kernel_launch(void* const* d_in, const int* in_sizes, int n_in,
                              void* d_out, int out_size, void* d_ws, size_t ws_size,
                              hipStream_t stream) {
    const float* hs     = (const float*)d_in[0];
    const float* latent = (const float*)d_in[1];
    const float* attnw  = (const float*)d_in[2];
    const float* attnb  = (const float*)d_in[3];
    const float* projw  = (const float*)d_in[4];
    const float* projb  = (const float*)d_in[5];
    const float* textw  = (const float*)d_in[6];
    const float* textb  = (const float*)d_in[7];
    const float* latw   = (const float*)d_in[8];
    const float* latb   = (const float*)d_in[9];

    char* ws = (char*)d_ws;
    size_t off = 0;
    auto alloc = [&](size_t bytes) {
        char* p = ws + off;
        off += (bytes + 255) & ~(size_t)255;
        return p;
    };
    u16* qkv    = (u16*)alloc((size_t)8192 * 3072 * 2);  // q(pre-scaled)|k|v bf16
    u16* hsbf   = (u16*)alloc((size_t)8192 * 1024 * 2);  // hs bf16, later attn_out
    u16* vfT    = (u16*)alloc((size_t)1024 * 8192 * 2);  // fused value, per-head transposed
    u16* attnWT = (u16*)alloc((size_t)3072 * 1024 * 2);  // c_attn_w^T bf16 [3072][1024]
    u16* projWT = (u16*)alloc((size_t)1024 * 1024 * 2);  // c_proj_w^T bf16
    u16* WtT    = (u16*)alloc((size_t)1024 * 1024 * 2);  // (sum_r text_w)^T bf16
    float* btf  = (float*)alloc(1024 * 4);
    float* lf   = (float*)alloc(4 * 1024 * 4);
    float* wsum = (float*)alloc((size_t)257 * 1024 * 4);

    cvt_bf16_kernel<<<8192, 256, 0, stream>>>(hs, (u32*)hsbf, 8192 * 1024 / 4);
    transpose_sum_bf16<<<dim3(96, 32), 256, 0, stream>>>(attnw, attnWT, 1024, 3072, 1, 0);
    transpose_sum_bf16<<<dim3(32, 32), 256, 0, stream>>>(projw, projWT, 1024, 1024, 1, 0);
    transpose_sum_bf16<<<dim3(32, 32), 256, 0, stream>>>(textw, WtT, 1024, 1024, 4, (long)1025 * 1024);
    btfull_kernel<<<4, 256, 0, stream>>>(textw, textb, btf);
    latw_sum_kernel<<<1028, 256, 0, stream>>>(latw, wsum);
    latfuse_kernel<<<dim3(4, 4), 256, 0, stream>>>(latent, wsum, latb, lf);

    // qkv = hs @ c_attn_w + c_attn_b, q-cols pre-scaled by 0.125*log2(e)
    gemm_bt<3><<<dim3(24, 64), 256, 0, stream>>>(
        (const bf16*)hsbf, 1024, (const bf16*)attnWT, 1024, qkv, 3072, 1024, attnb, nullptr);
    // vfT[o][s] = ((v @ Wt)[s][o] + btf[o]) * lf[b(s)][o]   (computed transposed)
    gemm_bt<2><<<dim3(64, 8), 256, 0, stream>>>(
        (const bf16*)WtT, 1024, (const bf16*)qkv + 2048, 3072, vfT, 8192, 1024, btf, lf);
    // attention -> hsbf (reused as attn_out)
    attn_kernel<<<dim3(16, 64), 256, 0, stream>>>((const bf16*)qkv, (const bf16*)vfT, hsbf);
    // out = attn @ c_proj_w + c_proj_b  (f32)
    gemm_bt<1><<<dim3(8, 64), 256, 0, stream>>>(
        (const bf16*)hsbf, 1024, (const bf16*)projWT, 1024, d_out, 1024, 1024, projb, nullptr);
}

// Round 7
// 405.853 us; speedup vs baseline: 1.0440x; 1.0440x over previous
//
#include <hip/hip_runtime.h>
#include <hip/hip_bf16.h>

typedef __bf16 bf16;
typedef __bf16 bf16x8 __attribute__((ext_vector_type(8)));
typedef float f32x4 __attribute__((ext_vector_type(4)));
typedef unsigned short u16;
typedef unsigned int u32;

// round-to-nearest-even f32 -> bf16 bits (host-side prep kernels)
__device__ __forceinline__ u16 f2bf_bits(float f) {
    union { float f; u32 u; } v;
    v.f = f;
    u32 r = v.u + 0x7FFFu + ((v.u >> 16) & 1u);
    return (u16)(r >> 16);
}

// natural pack: compiler emits v_cvt_pk_bf16_f32 (RNE)
__device__ __forceinline__ u32 pack_bf2(float a, float b) {
    union { __bf16 h[2]; u32 u; } v;
    v.h[0] = (__bf16)a;
    v.h[1] = (__bf16)b;
    return v.u;
}

__device__ __forceinline__ void gload_lds16(const void* g, void* l) {
    __builtin_amdgcn_global_load_lds((const __attribute__((address_space(1))) void*)g,
                                     (__attribute__((address_space(3))) void*)l, 16, 0, 0);
}

// ---------------------------------------------------------------------------
// Prep kernels
// ---------------------------------------------------------------------------

__global__ __launch_bounds__(256) void cvt_bf16_kernel(const float* __restrict__ in,
                                                       u32* __restrict__ out, int n4) {
    int i = blockIdx.x * 256 + threadIdx.x;
    if (i < n4) {
        float4 v = reinterpret_cast<const float4*>(in)[i];
        u32 lo = (u32)f2bf_bits(v.x) | ((u32)f2bf_bits(v.y) << 16);
        u32 hi = (u32)f2bf_bits(v.z) | ((u32)f2bf_bits(v.w) << 16);
        reinterpret_cast<uint2*>(out)[i] = make_uint2(lo, hi);
    }
}

// out[n][k] = bf16( sum_r in[r*slab + k*N + n] ), K,N multiples of 32
__global__ __launch_bounds__(256) void transpose_sum_bf16(const float* __restrict__ in,
                                                          u16* __restrict__ out,
                                                          int K, int N, int R, long slab) {
    __shared__ float tile[32][33];
    int x = threadIdx.x & 31, ty = threadIdx.x >> 5;
    int k0 = blockIdx.y * 32, n0 = blockIdx.x * 32;
    for (int yy = ty; yy < 32; yy += 8) {
        float s = 0.f;
        for (int r = 0; r < R; ++r)
            s += in[(size_t)r * slab + (size_t)(k0 + yy) * N + n0 + x];
        tile[yy][x] = s;
    }
    __syncthreads();
    for (int yy = ty; yy < 32; yy += 8)
        out[(size_t)(n0 + yy) * K + k0 + x] = f2bf_bits(tile[x][yy]);
}

// bt[o] = sum_r text_w[r][1024][o] + text_b[r][o]
__global__ __launch_bounds__(256) void btfull_kernel(const float* __restrict__ tw,
                                                     const float* __restrict__ tb,
                                                     float* __restrict__ bt) {
    int o = blockIdx.x * 256 + threadIdx.x;
    float s = 0.f;
    for (int r = 0; r < 4; ++r)
        s += tw[(size_t)r * 1025 * 1024 + (size_t)1024 * 1024 + o] + tb[r * 1024 + o];
    bt[o] = s;
}

// wsum[i][o] = sum_r lat_w[r][i][o]  (i in [0,257))
__global__ __launch_bounds__(256) void latw_sum_kernel(const float* __restrict__ lw,
                                                       float* __restrict__ wsum) {
    int i = blockIdx.x * 256 + threadIdx.x;
    if (i < 257 * 1024) {
        float s = 0.f;
        for (int r = 0; r < 4; ++r) s += lw[(size_t)r * 257 * 1024 + i];
        wsum[i] = s;
    }
}

// lf[b][o] = sum_{i<256} latent[b][i]*wsum[i][o] + wsum[256][o] + sum_r lat_b[r][o]
__global__ __launch_bounds__(256) void latfuse_kernel(const float* __restrict__ latent,
                                                      const float* __restrict__ wsum,
                                                      const float* __restrict__ lb,
                                                      float* __restrict__ lf) {
    __shared__ float lat[256];
    const int b = blockIdx.y;
    const int o = blockIdx.x * 256 + threadIdx.x;
    lat[threadIdx.x] = latent[b * 256 + threadIdx.x];
    __syncthreads();
    float acc = wsum[(size_t)256 * 1024 + o];
    for (int r = 0; r < 4; ++r) acc += lb[r * 1024 + o];
#pragma unroll 8
    for (int i = 0; i < 256; ++i) acc += lat[i] * wsum[(size_t)i * 1024 + o];
    lf[b * 1024 + o] = acc;
}

// ---------------------------------------------------------------------------
// GEMM: C[M,N] = A[M,K] @ BT[N,K]^T
// EPI 1: +bias[col] -> f32
// EPI 2: +bias[row], * lf[(col>>11)][row] -> bf16   (transposed value-fusion)
// EPI 3: +bias[col], then * 0.125*log2e for col<1024 (pre-scaled q) -> bf16
// m97 structure: 128x128 tile, BK=64, 4 waves, global_load_lds, linear LDS.
// ---------------------------------------------------------------------------
template <int EPI>
__global__ __launch_bounds__(256) void gemm_bt(const bf16* __restrict__ A, int lda,
                                               const bf16* __restrict__ BT, int ldb,
                                               void* __restrict__ Cout, int ldc, int K,
                                               const float* __restrict__ bias,
                                               const float* __restrict__ scale) {
    __shared__ __align__(16) char As[16384];  // 128 rows x 64 bf16, linear
    __shared__ __align__(16) char Bs[16384];
    const int tid = threadIdx.x;
    const int w = tid >> 6, l = tid & 63;

    // XCD-aware bijective swizzle (grids here are multiples of 8)
    const int nwgx = gridDim.x;
    const int nwg = nwgx * gridDim.y;
    const int wgid = blockIdx.y * nwgx + blockIdx.x;
    const int swz = (wgid & 7) * (nwg >> 3) + (wgid >> 3);
    const int m0 = (swz / nwgx) * 128, n0 = (swz % nwgx) * 128;
    const int wr = (w >> 1) * 64, wc = (w & 1) * 64;

    f32x4 acc[4][4] = {};
    const int kIters = K >> 6;

    const int srow = tid >> 3;             // 0..31
    const int scol = (tid & 7) * 8;        // element col within BK=64
    const size_t aBase = (size_t)(m0 + srow) * lda + scol;
    const size_t bBase = (size_t)(n0 + srow) * ldb + scol;
    char* AsW = As + w * 1024;             // wave-uniform LDS base
    char* BsW = Bs + w * 1024;

    for (int kt = 0; kt < kIters; ++kt) {
        const int kk = kt << 6;
#pragma unroll
        for (int i = 0; i < 4; ++i) {
            gload_lds16(A + aBase + (size_t)(i * 32) * lda + kk, AsW + i * 4096);
            gload_lds16(BT + bBase + (size_t)(i * 32) * ldb + kk, BsW + i * 4096);
        }
        __syncthreads();  // drains vmcnt -> LDS tile ready
#pragma unroll
        for (int dc = 0; dc < 2; ++dc) {
            bf16x8 af[4], bfr[4];
#pragma unroll
            for (int m = 0; m < 4; ++m) {
                int off = (wr + m * 16 + (l & 15)) * 128 + dc * 64 + (l >> 4) * 16;
                af[m] = *reinterpret_cast<const bf16x8*>(As + off);
            }
#pragma unroll
            for (int n = 0; n < 4; ++n) {
                int off = (wc + n * 16 + (l & 15)) * 128 + dc * 64 + (l >> 4) * 16;
                bfr[n] = *reinterpret_cast<const bf16x8*>(Bs + off);
            }
#pragma unroll
            for (int m = 0; m < 4; ++m)
#pragma unroll
                for (int n = 0; n < 4; ++n)
                    acc[m][n] = __builtin_amdgcn_mfma_f32_16x16x32_bf16(af[m], bfr[n], acc[m][n], 0, 0, 0);
        }
        __syncthreads();  // tile consumed, safe to overwrite
    }

    const bool qtile = (EPI == 3) && (n0 < 1024);  // block-uniform
#pragma unroll
    for (int m = 0; m < 4; ++m) {
#pragma unroll
        for (int n = 0; n < 4; ++n) {
#pragma unroll
            for (int r = 0; r < 4; ++r) {
                int grow = m0 + wr + m * 16 + (l >> 4) * 4 + r;
                int gcol = n0 + wc + n * 16 + (l & 15);
                float v = acc[m][n][r];
                if (EPI == 1 || EPI == 3) v += bias[gcol];
                if (EPI == 3 && qtile) v *= 0.18033688011f;  // 0.125*log2(e)
                if (EPI == 2) {
                    v += bias[grow];
                    v *= scale[((gcol >> 11) << 10) | grow];
                }
                if (EPI == 1)
                    reinterpret_cast<float*>(Cout)[(size_t)grow * ldc + gcol] = v;
                else
                    reinterpret_cast<u16*>(Cout)[(size_t)grow * ldc + gcol] = f2bf_bits(v);
            }
        }
    }
}

// ---------------------------------------------------------------------------
// Flash attention, causal. qkv bf16 [8192][3072] (q pre-scaled | k | v cols),
// vfT bf16 [1024 o][8192 s], out bf16 [8192][1024].
// grid (64, 16): blockIdx.x = bh, blockIdx.y -> qt = 15-y (heavy tiles first).
// Linear id = y*64 + bh, and 64 % 8 == 0 => all 16 q-tile blocks of one bh
// land on the SAME XCD (round-robin id%8), so K/V staging re-reads hit that
// XCD's L2 (per-XCD set: 8 bh x 512 KB = 4 MB). 1024 blocks = 4/CU.
// 256 threads = 4 waves x 32 q-rows (2 qf chains/wave for ILP, R6 lesson).
// K/V^T double-buffered in LDS (32 KB), P in-register (cvt_pk + shfl routes).
// NOTE: no min-waves pin -- (256,4) forced VGPR<=128 and spilled (R4).
// ---------------------------------------------------------------------------
__global__ __launch_bounds__(256) void attn_kernel(const bf16* __restrict__ qkv,
                                                   const bf16* __restrict__ vfT,
                                                   u16* __restrict__ out) {
    __shared__ __align__(16) char Kl[2][8192];     // [buf][64 kv][64 d] chunk-swizzled
    __shared__ __align__(16) char Vt[2][8192];     // [buf][64 hd][64 kv] chunk-swizzled
    const int tid = threadIdx.x, w = tid >> 6, l = tid & 63;
    const int bh = blockIdx.x, b = bh >> 4, h = bh & 15;
    const int qt = 15 - blockIdx.y;                // heavy first (LPT packing)
    const int q0 = qt * 128;
    const size_t rowQ = (size_t)(b * 2048 + q0 + w * 32);

    // staging geometry: wave w covers LDS rows w*8+i*32+(l>>3), chunk l&7;
    // source chunk pre-swizzled: cs = (l&7) ^ (l>>3)
    const int srowL = (l >> 3);                    // 0..7 within 8-row stripe
    const int cs = ((l & 7) ^ srowL) * 8;          // element offset of source chunk

    // Q fragments (B-operand layout for swapped QK^T); q pre-scaled
    bf16x8 qfr[2][2];
#pragma unroll
    for (int qf = 0; qf < 2; ++qf)
#pragma unroll
        for (int dc = 0; dc < 2; ++dc)
            qfr[qf][dc] = *reinterpret_cast<const bf16x8*>(
                qkv + (rowQ + qf * 16 + (l & 15)) * 3072 + h * 64 + dc * 32 + (l >> 4) * 8);

    f32x4 oacc[2][4] = {};
    float mrun[2] = {-1e30f, -1e30f};
    float lrun[2] = {0.f, 0.f};
    const int nt = (q0 + 128) >> 6;
    const int qmaxw = q0 + w * 32 + 31;

    auto stage = [&](int t, int buf) {
        const size_t kvb = (size_t)(b * 2048 + t * 64);
#pragma unroll
        for (int i = 0; i < 2; ++i) {
            int r = w * 8 + i * 32 + srowL;
            gload_lds16(qkv + (kvb + r) * 3072 + 1024 + h * 64 + cs,
                        Kl[buf] + w * 1024 + i * 4096);
            gload_lds16(vfT + (size_t)(h * 64 + r) * 8192 + kvb + cs,
                        Vt[buf] + w * 1024 + i * 4096);
        }
    };

    stage(0, 0);
    int cur = 0;
    for (int t = 0; t < nt; ++t) {
        __syncthreads();  // vmcnt(0)+barrier: buf[cur] ready, buf[cur^1] free
        if (t + 1 < nt) stage(t + 1, cur ^ 1);
        const int kv0 = t * 64;
        if (kv0 <= qmaxw) {
            const char* Kb = Kl[cur];
            const char* Vb = Vt[cur];
            // QK^T (swapped): sacc[kf][qf] = S^T[kv, q], already in log2 units
            f32x4 sacc[4][2] = {};
            __builtin_amdgcn_s_setprio(1);
#pragma unroll
            for (int dc = 0; dc < 2; ++dc) {
#pragma unroll
                for (int kf = 0; kf < 4; ++kf) {
                    int row = kf * 16 + (l & 15);
                    int off = (row * 128 + dc * 64 + (l >> 4) * 16) ^ ((row & 7) << 4);
                    bf16x8 kfr = *reinterpret_cast<const bf16x8*>(Kb + off);
#pragma unroll
                    for (int qf = 0; qf < 2; ++qf)
                        sacc[kf][qf] = __builtin_amdgcn_mfma_f32_16x16x32_bf16(
                            kfr, qfr[qf][dc], sacc[kf][qf], 0, 0, 0);
                }
            }
            __builtin_amdgcn_s_setprio(0);
            const bool needMask = (kv0 + 63) > (q0 + w * 32);
            bf16x8 pa[2][2];  // [qf][kc] PV A-fragments, built in-register
#pragma unroll
            for (int qf = 0; qf < 2; ++qf) {
                int qg = q0 + w * 32 + qf * 16 + (l & 15);
                float p[4][4];
                float tmax = -1e30f;
#pragma unroll
                for (int kf = 0; kf < 4; ++kf)
#pragma unroll
                    for (int r = 0; r < 4; ++r) {
                        float s = sacc[kf][qf][r];
                        if (needMask) {
                            int kvg = kv0 + kf * 16 + (l >> 4) * 4 + r;
                            if (kvg > qg) s = -1e30f;
                        }
                        p[kf][r] = s;
                        tmax = fmaxf(tmax, s);
                    }
                tmax = fmaxf(tmax, __shfl_xor(tmax, 16));
                tmax = fmaxf(tmax, __shfl_xor(tmax, 32));
                // defer-max (T13): only rescale when max grows by > 8 (log2 domain)
                if (!__all(tmax <= mrun[qf] + 8.f)) {
                    float mnew = fmaxf(mrun[qf], tmax);
                    float alpha = exp2f(mrun[qf] - mnew);
                    mrun[qf] = mnew;
                    lrun[qf] *= alpha;
#pragma unroll
                    for (int r = 0; r < 4; ++r) {
                        float al = __shfl(alpha, (l >> 4) * 4 + r);
#pragma unroll
                        for (int hf = 0; hf < 4; ++hf) oacc[qf][hf][r] *= al;
                    }
                }
                const float m = mrun[qf];
                float rsum = 0.f;
#pragma unroll
                for (int kf = 0; kf < 4; ++kf) {
                    float p0 = exp2f(p[kf][0] - m), p1 = exp2f(p[kf][1] - m);
                    float p2 = exp2f(p[kf][2] - m), p3 = exp2f(p[kf][3] - m);
                    p[kf][0] = p0; p[kf][1] = p1; p[kf][2] = p2; p[kf][3] = p3;
                    rsum += (p0 + p1) + (p2 + p3);
                }
                rsum += __shfl_xor(rsum, 16);
                rsum += __shfl_xor(rsum, 32);
                lrun[qf] += rsum;
                // pack to bf16 pairs: c[kf][h] = (P[kv=kf*16+g*4+2h], kv+1)
                u32 c[4][2];
#pragma unroll
                for (int kf = 0; kf < 4; ++kf) {
                    c[kf][0] = pack_bf2(p[kf][0], p[kf][1]);
                    c[kf][1] = pack_bf2(p[kf][2], p[kf][3]);
                }
                // register re-layout to PV A-frag: lane needs kv=kc*32+g*8+j.
                // routes (verified): g01: A<-A.even, B<-C.even, C<-A.odd, D<-C.odd
                //                    g23: A<-B.even, B<-D.even, C<-B.odd, D<-D.odd
#pragma unroll
                for (int kc = 0; kc < 2; ++kc) {
                    u32 wlo[2], whi[2];
#pragma unroll
                    for (int hh = 0; hh < 2; ++hh) {
                        u32 oe = c[2 * kc][hh], oo = c[2 * kc + 1][hh];
                        u32 xoe = (u32)__shfl_xor((int)oe, 32);
                        u32 xoo = (u32)__shfl_xor((int)oo, 32);
                        u32 P1 = (l & 32) ? xoo : oe;
                        u32 P2 = (l & 32) ? oo : xoe;
                        u32 z = (l & 16) ? P1 : P2;
                        u32 xz = (u32)__shfl_xor((int)z, 16);
                        wlo[hh] = (l & 16) ? xz : P1;
                        whi[hh] = (l & 16) ? P2 : xz;
                    }
                    union { u32 u[4]; bf16x8 v; } pv;
                    pv.u[0] = wlo[0]; pv.u[1] = wlo[1];
                    pv.u[2] = whi[0]; pv.u[3] = whi[1];
                    pa[qf][kc] = pv.v;
                }
            }
            // PV: oacc[qf][hf] += P[q][kv] * V^T[hd][kv]^T
            __builtin_amdgcn_s_setprio(1);
#pragma unroll
            for (int kc = 0; kc < 2; ++kc) {
#pragma unroll
                for (int hf = 0; hf < 4; ++hf) {
                    int hd = hf * 16 + (l & 15);
                    int off = (hd * 128 + kc * 64 + (l >> 4) * 16) ^ ((hd & 7) << 4);
                    bf16x8 vb = *reinterpret_cast<const bf16x8*>(Vb + off);
#pragma unroll
                    for (int qf = 0; qf < 2; ++qf)
                        oacc[qf][hf] = __builtin_amdgcn_mfma_f32_16x16x32_bf16(
                            pa[qf][kc], vb, oacc[qf][hf], 0, 0, 0);
                }
            }
            __builtin_amdgcn_s_setprio(0);
        }
        cur ^= 1;
    }

#pragma unroll
    for (int qf = 0; qf < 2; ++qf) {
#pragma unroll
        for (int r = 0; r < 4; ++r) {
            float linv = 1.0f / __shfl(lrun[qf], (l >> 4) * 4 + r);
            size_t grow = rowQ + qf * 16 + (l >> 4) * 4 + r;
#pragma unroll
            for (int hf = 0; hf < 4; ++hf)
                out[grow * 1024 + h * 64 + hf * 16 + (l & 15)] =
                    f2bf_bits(oacc[qf][hf][r] * linv);
        }
    }
}

// ---------------------------------------------------------------------------

extern "C" void kernel_launch(void* const* d_in, const int* in_sizes, int n_in,
                              void* d_out, int out_size, void* d_ws, size_t ws_size,
                              hipStream_t stream) {
    const float* hs     = (const float*)d_in[0];
    const float* latent = (const float*)d_in[1];
    const float* attnw  = (const float*)d_in[2];
    const float* attnb  = (const float*)d_in[3];
    const float* projw  = (const float*)d_in[4];
    const float* projb  = (const float*)d_in[5];
    const float* textw  = (const float*)d_in[6];
    const float* textb  = (const float*)d_in[7];
    const float* latw   = (const float*)d_in[8];
    const float* latb   = (const float*)d_in[9];

    char* ws = (char*)d_ws;
    size_t off = 0;
    auto alloc = [&](size_t bytes) {
        char* p = ws + off;
        off += (bytes + 255) & ~(size_t)255;
        return p;
    };
    u16* qkv    = (u16*)alloc((size_t)8192 * 3072 * 2);  // q(pre-scaled)|k|v bf16
    u16* hsbf   = (u16*)alloc((size_t)8192 * 1024 * 2);  // hs bf16, later attn_out
    u16* vfT    = (u16*)alloc((size_t)1024 * 8192 * 2);  // fused value, per-head transposed
    u16* attnWT = (u16*)alloc((size_t)3072 * 1024 * 2);  // c_attn_w^T bf16 [3072][1024]
    u16* projWT = (u16*)alloc((size_t)1024 * 1024 * 2);  // c_proj_w^T bf16
    u16* WtT    = (u16*)alloc((size_t)1024 * 1024 * 2);  // (sum_r text_w)^T bf16
    float* btf  = (float*)alloc(1024 * 4);
    float* lf   = (float*)alloc(4 * 1024 * 4);
    float* wsum = (float*)alloc((size_t)257 * 1024 * 4);

    cvt_bf16_kernel<<<8192, 256, 0, stream>>>(hs, (u32*)hsbf, 8192 * 1024 / 4);
    transpose_sum_bf16<<<dim3(96, 32), 256, 0, stream>>>(attnw, attnWT, 1024, 3072, 1, 0);
    transpose_sum_bf16<<<dim3(32, 32), 256, 0, stream>>>(projw, projWT, 1024, 1024, 1, 0);
    transpose_sum_bf16<<<dim3(32, 32), 256, 0, stream>>>(textw, WtT, 1024, 1024, 4, (long)1025 * 1024);
    btfull_kernel<<<4, 256, 0, stream>>>(textw, textb, btf);
    latw_sum_kernel<<<1028, 256, 0, stream>>>(latw, wsum);
    latfuse_kernel<<<dim3(4, 4), 256, 0, stream>>>(latent, wsum, latb, lf);

    // qkv = hs @ c_attn_w + c_attn_b, q-cols pre-scaled by 0.125*log2(e)
    gemm_bt<3><<<dim3(24, 64), 256, 0, stream>>>(
        (const bf16*)hsbf, 1024, (const bf16*)attnWT, 1024, qkv, 3072, 1024, attnb, nullptr);
    // vfT[o][s] = ((v @ Wt)[s][o] + btf[o]) * lf[b(s)][o]   (computed transposed)
    gemm_bt<2><<<dim3(64, 8), 256, 0, stream>>>(
        (const bf16*)WtT, 1024, (const bf16*)qkv + 2048, 3072, vfT, 8192, 1024, btf, lf);
    // attention -> hsbf (reused as attn_out)
    attn_kernel<<<dim3(64, 16), 256, 0, stream>>>((const bf16*)qkv, (const bf16*)vfT, hsbf);
    // out = attn @ c_proj_w + c_proj_b  (f32)
    gemm_bt<1><<<dim3(8, 64), 256, 0, stream>>>(
        (const bf16*)hsbf, 1024, (const bf16*)projWT, 1024, d_out, 1024, 1024, projb, nullptr);
}